// Round 8
// baseline (55.145 us; speedup 1.0000x reference)
//
#include <hip/hip_runtime.h>
#include <hip/hip_bf16.h>
#include <stdint.h>

#define LRELU_ALPHA 0.2f
#define L2E 1.44269504f

constexpr int BB = 8, NN = 2048, FIN = 128, FOUT = 64;
constexpr int GEMM_ROWS = 32;
constexpr int NBLK_G = BB * NN / GEMM_ROWS;   // 512 blocks / partial maxes

typedef __attribute__((ext_vector_type(8))) short short8;
typedef __attribute__((ext_vector_type(4))) float f32x4;

__device__ __forceinline__ ushort bf16rn(float f) {
    __hip_bfloat16 h = __float2bfloat16(f);
    return *reinterpret_cast<ushort*>(&h);
}

// ---------------- Kernel 1: Wh = h @ W (fp32) -> packed bf16 WhP + s1/s2/pmax
// (verified; ~3 us class)
#define HS 132
__global__ __launch_bounds__(256) void k_gemm_hw(const float* __restrict__ h,
                                                 const float* __restrict__ W,
                                                 const float* __restrict__ a,
                                                 ushort* __restrict__ WhP,
                                                 float* __restrict__ s1,
                                                 float* __restrict__ s2,
                                                 float* __restrict__ pmax) {
    __shared__ float hs[GEMM_ROWS * HS];
    __shared__ __align__(16) ushort fragbuf[2048];
    __shared__ float smax[16];
    const int tid = threadIdx.x;
    const int base = blockIdx.x * GEMM_ROWS;

    #pragma unroll
    for (int rep = 0; rep < 4; ++rep) {
        int flat4 = rep * 256 + tid;
        int row = flat4 >> 5, k4 = flat4 & 31;
        float4 v = *reinterpret_cast<const float4*>(h + (size_t)(base + row) * FIN + k4 * 4);
        *reinterpret_cast<float4*>(&hs[row * HS + k4 * 4]) = v;
    }
    __syncthreads();

    const int tr = tid >> 4;
    const int tc = tid & 15;
    float acc[2][4] = {};
    #pragma unroll 4
    for (int k = 0; k < FIN; ++k) {
        float4 wv = *reinterpret_cast<const float4*>(W + (size_t)k * FOUT + tc * 4);
        #pragma unroll
        for (int r = 0; r < 2; ++r) {
            float hv = hs[(tr * 2 + r) * HS + k];
            acc[r][0] = fmaf(hv, wv.x, acc[r][0]);
            acc[r][1] = fmaf(hv, wv.y, acc[r][1]);
            acc[r][2] = fmaf(hv, wv.z, acc[r][2]);
            acc[r][3] = fmaf(hv, wv.w, acc[r][3]);
        }
    }

    #pragma unroll
    for (int r = 0; r < 2; ++r) {
        const int jloc = tr * 2 + r;
        const int e = jloc & 7, kgrp = jloc >> 3;
        #pragma unroll
        for (int c = 0; c < 4; ++c) {
            const int col = tc * 4 + c;
            fragbuf[((col >> 4) * 64 + kgrp * 16 + (col & 15)) * 8 + e] = bf16rn(acc[r][c]);
        }
    }

    float a1c[4], a2c[4];
    #pragma unroll
    for (int c = 0; c < 4; ++c) {
        a1c[c] = a[tc * 4 + c];
        a2c[c] = a[FOUT + tc * 4 + c];
    }
    float maxp2 = -3.4e38f;
    #pragma unroll
    for (int r = 0; r < 2; ++r) {
        float p1 = acc[r][0] * a1c[0] + acc[r][1] * a1c[1] + acc[r][2] * a1c[2] + acc[r][3] * a1c[3];
        float p2 = acc[r][0] * a2c[0] + acc[r][1] * a2c[1] + acc[r][2] * a2c[2] + acc[r][3] * a2c[3];
        #pragma unroll
        for (int off = 1; off < 16; off <<= 1) {
            p1 += __shfl_xor(p1, off);
            p2 += __shfl_xor(p2, off);
        }
        if (tc == 0) {
            s1[base + tr * 2 + r] = p1;
            s2[base + tr * 2 + r] = p2;
            maxp2 = fmaxf(maxp2, p2);
        }
    }
    if (tc == 0) smax[tr] = maxp2;
    __syncthreads();

    const size_t region = ((size_t)((base >> 11) * 64 + ((base & 2047) >> 5))) * 2048;
    *reinterpret_cast<uint4*>(WhP + region + tid * 8) =
        *reinterpret_cast<const uint4*>(fragbuf + tid * 8);

    if (tid == 0) {
        float mm = smax[0];
        #pragma unroll
        for (int i = 1; i < 16; ++i) mm = fmaxf(mm, smax[i]);
        pmax[blockIdx.x] = mm;
    }
}

// ---------------- Kernel 2: flash-style masked softmax + MFMA PV ----------
// 16 rows/block, 4 waves x 512-j slices (16 tiles of 32 j), 256 threads.
// DEPTH-3 register prefetch on the adj HBM stream (4 rotating buffers,
// unroll 4 -> static indices). b-frags/s2 loaded at point of use (L1/L2).
// S via 5th MFMA against all-ones B (bit-consistent with numerator).
// __launch_bounds__(256,4): VGPR cap 128 (est ~110, no spill), 4 waves/SIMD.
__global__ __launch_bounds__(256, 4) void k_attn(const float* __restrict__ adj,
                                                 const ushort* __restrict__ WhP,
                                                 const float* __restrict__ s1,
                                                 const float* __restrict__ s2,
                                                 const float* __restrict__ pmax,
                                                 float* __restrict__ out) {
    __shared__ float lacc[4][16][68];
    __shared__ float lS[4][16];

    const int tid = threadIdx.x;
    const int l = tid & 63, w = tid >> 6;      // w in [0,4)
    const int li = l & 15, lk = l >> 4;
    const int blk = blockIdx.x;
    const int b = blk >> 7;
    const int rowbase = blk * 16;
    const int row_i = rowbase + li;

    float m = -3.4e38f;
    #pragma unroll
    for (int t = 0; t < 8; ++t) m = fmaxf(m, pmax[l + 64 * t]);
    #pragma unroll
    for (int off = 32; off > 0; off >>= 1) m = fmaxf(m, __shfl_xor(m, off));

    const float s1i = s1[row_i];
    const float cp = s1i + m;
    const float cL = fmaxf(cp, LRELU_ALPHA * cp) * L2E;   // c*log2e, c >= max e_ij

    const float* __restrict__ adjp = adj + (size_t)row_i * NN + w * 512 + lk * 8;
    const float* __restrict__ s2p  = s2 + (size_t)b * NN + w * 512 + lk * 8;
    const ushort* __restrict__ whp = WhP + (size_t)b * 131072 + (size_t)(w * 16) * 2048 + l * 8;

    f32x4 acc0 = {0.f, 0.f, 0.f, 0.f};
    f32x4 acc1 = {0.f, 0.f, 0.f, 0.f};
    f32x4 acc2 = {0.f, 0.f, 0.f, 0.f};
    f32x4 acc3 = {0.f, 0.f, 0.f, 0.f};
    f32x4 accS = {0.f, 0.f, 0.f, 0.f};
    short8 ones;
    #pragma unroll
    for (int e = 0; e < 8; ++e) ones[e] = (short)0x3F80;   // bf16 1.0

    // depth-3 rotating adj prefetch buffers
    float4 pa[4][2];
    pa[0][0] = *reinterpret_cast<const float4*>(adjp);
    pa[0][1] = *reinterpret_cast<const float4*>(adjp + 4);
    pa[1][0] = *reinterpret_cast<const float4*>(adjp + 32);
    pa[1][1] = *reinterpret_cast<const float4*>(adjp + 36);
    pa[2][0] = *reinterpret_cast<const float4*>(adjp + 64);
    pa[2][1] = *reinterpret_cast<const float4*>(adjp + 68);

    #pragma unroll 4
    for (int t = 0; t < 16; ++t) {
        // issue adj load for tile t+3 into the buffer freed at t-1
        const int tl = (t + 3 < 16) ? t + 3 : 15;      // clamped (redundant tail)
        pa[(t + 3) & 3][0] = *reinterpret_cast<const float4*>(adjp + tl * 32);
        pa[(t + 3) & 3][1] = *reinterpret_cast<const float4*>(adjp + tl * 32 + 4);

        const float4 a0 = pa[t & 3][0];
        const float4 a1 = pa[t & 3][1];
        const float4 v0 = *reinterpret_cast<const float4*>(s2p + t * 32);
        const float4 v1 = *reinterpret_cast<const float4*>(s2p + t * 32 + 4);

        short8 af;
        {
            float ev, lr, ex;
#define DOE(idx, AV, SV)                                                      \
            ev = s1i + (SV);                                                  \
            lr = fmaxf(ev, LRELU_ALPHA * ev);                                 \
            ex = exp2f(fmaf(lr, L2E, -cL));                                   \
            af[idx] = (short)bf16rn((AV) * ex);
            DOE(0, a0.x, v0.x) DOE(1, a0.y, v0.y) DOE(2, a0.z, v0.z) DOE(3, a0.w, v0.w)
            DOE(4, a1.x, v1.x) DOE(5, a1.y, v1.y) DOE(6, a1.z, v1.z) DOE(7, a1.w, v1.w)
#undef DOE
        }

        const ushort* p_ = whp + t * 2048;
        const short8 b0 = *reinterpret_cast<const short8*>(p_);
        const short8 b1 = *reinterpret_cast<const short8*>(p_ + 512);
        const short8 b2 = *reinterpret_cast<const short8*>(p_ + 1024);
        const short8 b3 = *reinterpret_cast<const short8*>(p_ + 1536);

        acc0 = __builtin_amdgcn_mfma_f32_16x16x32_bf16(af, b0, acc0, 0, 0, 0);
        acc1 = __builtin_amdgcn_mfma_f32_16x16x32_bf16(af, b1, acc1, 0, 0, 0);
        acc2 = __builtin_amdgcn_mfma_f32_16x16x32_bf16(af, b2, acc2, 0, 0, 0);
        acc3 = __builtin_amdgcn_mfma_f32_16x16x32_bf16(af, b3, acc3, 0, 0, 0);
        accS = __builtin_amdgcn_mfma_f32_16x16x32_bf16(af, ones, accS, 0, 0, 0);
    }

    // accS is in D layout: accS[r] = S(row lk*4+r) on every lane
    if (li == 0) {
        #pragma unroll
        for (int r = 0; r < 4; ++r) lS[w][lk * 4 + r] = accS[r];
    }
    #pragma unroll
    for (int r = 0; r < 4; ++r) {
        lacc[w][lk * 4 + r][0 * 16 + li] = acc0[r];
        lacc[w][lk * 4 + r][1 * 16 + li] = acc1[r];
        lacc[w][lk * 4 + r][2 * 16 + li] = acc2[r];
        lacc[w][lk * 4 + r][3 * 16 + li] = acc3[r];
    }
    __syncthreads();

    // combine: 1024 outputs, 4 per thread
    #pragma unroll
    for (int q = 0; q < 4; ++q) {
        const int idx = q * 256 + tid;
        const int row = idx >> 6, col = idx & 63;
        float v = lacc[0][row][col] + lacc[1][row][col] + lacc[2][row][col] + lacc[3][row][col];
        float S = lS[0][row] + lS[1][row] + lS[2][row] + lS[3][row];
        float o = v / S;
        o = o > 0.f ? o : expm1f(o);
        out[(size_t)(rowbase + row) * FOUT + col] = o;
    }
}

// ---------------------------------------------------------------------------
extern "C" void kernel_launch(void* const* d_in, const int* in_sizes, int n_in,
                              void* d_out, int out_size, void* d_ws, size_t ws_size,
                              hipStream_t stream) {
    (void)in_sizes; (void)n_in; (void)out_size; (void)ws_size;
    const float* h   = (const float*)d_in[0];
    const float* adj = (const float*)d_in[1];
    const float* W   = (const float*)d_in[2];
    const float* a   = (const float*)d_in[3];
    float* out = (float*)d_out;

    ushort* WhP = (ushort*)d_ws;                          // 2 MB
    float* s1w  = (float*)(WhP + (size_t)BB * NN * FOUT);
    float* s2w  = s1w + (size_t)BB * NN;
    float* pmaxw = s2w + (size_t)BB * NN;                 // NBLK_G floats

    k_gemm_hw<<<NBLK_G, 256, 0, stream>>>(h, W, a, WhP, s1w, s2w, pmaxw);
    k_attn<<<BB * NN / 16, 256, 0, stream>>>(adj, WhP, s1w, s2w, pmaxw, out);
}

// Round 9
// 45.576 us; speedup vs baseline: 1.2100x; 1.2100x over previous
//
#include <hip/hip_runtime.h>
#include <hip/hip_bf16.h>
#include <stdint.h>

#define LRELU_ALPHA 0.2f

constexpr int BB = 8, NN = 2048, FIN = 128, FOUT = 64;
constexpr int GEMM_ROWS = 32;
constexpr int NBLK_G = BB * NN / GEMM_ROWS;   // 512 blocks / partial maxes

typedef __attribute__((ext_vector_type(8))) short short8;
typedef __attribute__((ext_vector_type(4))) float f32x4;

__device__ __forceinline__ ushort bf16rn(float f) {
    __hip_bfloat16 h = __float2bfloat16(f);
    return *reinterpret_cast<ushort*>(&h);
}

// ---------------- Kernel 1: Wh = h @ W (fp32) -> packed bf16 WhP + s1/s2/pmax
// (verified; ~3 us class)
#define HS 132
__global__ __launch_bounds__(256) void k_gemm_hw(const float* __restrict__ h,
                                                 const float* __restrict__ W,
                                                 const float* __restrict__ a,
                                                 ushort* __restrict__ WhP,
                                                 float* __restrict__ s1,
                                                 float* __restrict__ s2,
                                                 float* __restrict__ pmax) {
    __shared__ float hs[GEMM_ROWS * HS];
    __shared__ __align__(16) ushort fragbuf[2048];
    __shared__ float smax[16];
    const int tid = threadIdx.x;
    const int base = blockIdx.x * GEMM_ROWS;

    #pragma unroll
    for (int rep = 0; rep < 4; ++rep) {
        int flat4 = rep * 256 + tid;
        int row = flat4 >> 5, k4 = flat4 & 31;
        float4 v = *reinterpret_cast<const float4*>(h + (size_t)(base + row) * FIN + k4 * 4);
        *reinterpret_cast<float4*>(&hs[row * HS + k4 * 4]) = v;
    }
    __syncthreads();

    const int tr = tid >> 4;
    const int tc = tid & 15;
    float acc[2][4] = {};
    #pragma unroll 4
    for (int k = 0; k < FIN; ++k) {
        float4 wv = *reinterpret_cast<const float4*>(W + (size_t)k * FOUT + tc * 4);
        #pragma unroll
        for (int r = 0; r < 2; ++r) {
            float hv = hs[(tr * 2 + r) * HS + k];
            acc[r][0] = fmaf(hv, wv.x, acc[r][0]);
            acc[r][1] = fmaf(hv, wv.y, acc[r][1]);
            acc[r][2] = fmaf(hv, wv.z, acc[r][2]);
            acc[r][3] = fmaf(hv, wv.w, acc[r][3]);
        }
    }

    #pragma unroll
    for (int r = 0; r < 2; ++r) {
        const int jloc = tr * 2 + r;
        const int e = jloc & 7, kgrp = jloc >> 3;
        #pragma unroll
        for (int c = 0; c < 4; ++c) {
            const int col = tc * 4 + c;
            fragbuf[((col >> 4) * 64 + kgrp * 16 + (col & 15)) * 8 + e] = bf16rn(acc[r][c]);
        }
    }

    float a1c[4], a2c[4];
    #pragma unroll
    for (int c = 0; c < 4; ++c) {
        a1c[c] = a[tc * 4 + c];
        a2c[c] = a[FOUT + tc * 4 + c];
    }
    float maxp2 = -3.4e38f;
    #pragma unroll
    for (int r = 0; r < 2; ++r) {
        float p1 = acc[r][0] * a1c[0] + acc[r][1] * a1c[1] + acc[r][2] * a1c[2] + acc[r][3] * a1c[3];
        float p2 = acc[r][0] * a2c[0] + acc[r][1] * a2c[1] + acc[r][2] * a2c[2] + acc[r][3] * a2c[3];
        #pragma unroll
        for (int off = 1; off < 16; off <<= 1) {
            p1 += __shfl_xor(p1, off);
            p2 += __shfl_xor(p2, off);
        }
        if (tc == 0) {
            s1[base + tr * 2 + r] = p1;
            s2[base + tr * 2 + r] = p2;
            maxp2 = fmaxf(maxp2, p2);
        }
    }
    if (tc == 0) smax[tr] = maxp2;
    __syncthreads();

    const size_t region = ((size_t)((base >> 11) * 64 + ((base & 2047) >> 5))) * 2048;
    *reinterpret_cast<uint4*>(WhP + region + tid * 8) =
        *reinterpret_cast<const uint4*>(fragbuf + tid * 8);

    if (tid == 0) {
        float mm = smax[0];
        #pragma unroll
        for (int i = 1; i < 16; ++i) mm = fmaxf(mm, smax[i]);
        pmax[blockIdx.x] = mm;
    }
}

// ---------------- Kernel 2: separable-exp masked softmax + MFMA PV ----------
// Identity: exp(lrelu(s1_i+s2_j) - c_i) == max(e1p_i*E2p_j, e1n_i*E2n_j)
//   cp = s1_i + m2,  c_i = lrelu(cp)
//   e1p = exp(0.8*min(cp,0)),  e1n = exp(-0.8*max(cp,0))
//   E2p_j = exp(s2_j - m2),    E2n_j = exp(0.2*(s2_j - m2))
// (ratio p/q = exp(0.8*(s1+s2)) so fmaxf performs the lrelu branch select).
// E2 tables in LDS per block; per-element cost: 3 mul + 1 max + 1.5 pack.
// bf16 pack: round-half-up (+0x8000) then one v_perm per pair.
// S via all-ones-B MFMA (bit-consistent with numerator fragments).
__global__ __launch_bounds__(256, 4) void k_attn(const float* __restrict__ adj,
                                                 const ushort* __restrict__ WhP,
                                                 const float* __restrict__ s1,
                                                 const float* __restrict__ s2,
                                                 const float* __restrict__ pmax,
                                                 float* __restrict__ out) {
    __shared__ float2 e2buf[NN];        // 16 KB: {E2p, E2n} per j
    __shared__ float lacc[4][16][68];
    __shared__ float lS[4][16];

    const int tid = threadIdx.x;
    const int l = tid & 63, w = tid >> 6;      // w in [0,4)
    const int li = l & 15, lk = l >> 4;
    const int blk = blockIdx.x;
    const int b = blk >> 7;
    const int rowbase = blk * 16;
    const int row_i = rowbase + li;

    // global max m2 of s2 from 512 partials (L2-hot)
    float m = -3.4e38f;
    #pragma unroll
    for (int t = 0; t < 8; ++t) m = fmaxf(m, pmax[l + 64 * t]);
    #pragma unroll
    for (int off = 32; off > 0; off >>= 1) m = fmaxf(m, __shfl_xor(m, off));

    // fill E2 tables (whole batch-row range, 8 j per thread)
    const float* __restrict__ s2B = s2 + (size_t)b * NN;
    #pragma unroll
    for (int k = 0; k < 8; ++k) {
        const int j = k * 256 + tid;
        const float d = s2B[j] - m;
        e2buf[j] = make_float2(__expf(d), __expf(LRELU_ALPHA * d));
    }

    const float s1i = s1[row_i];
    const float cp = s1i + m;
    const float e1p = __expf(0.8f * fminf(cp, 0.f));
    const float e1n = __expf(-0.8f * fmaxf(cp, 0.f));

    __syncthreads();

    const float* __restrict__ adjp = adj + (size_t)row_i * NN + w * 512 + lk * 8;
    const ushort* __restrict__ whp = WhP + (size_t)b * 131072 + (size_t)(w * 16) * 2048 + l * 8;
    const float2* __restrict__ e2w = e2buf + w * 512 + lk * 8;

    f32x4 acc0 = {0.f, 0.f, 0.f, 0.f};
    f32x4 acc1 = {0.f, 0.f, 0.f, 0.f};
    f32x4 acc2 = {0.f, 0.f, 0.f, 0.f};
    f32x4 acc3 = {0.f, 0.f, 0.f, 0.f};
    f32x4 accS = {0.f, 0.f, 0.f, 0.f};
    short8 ones;
    #pragma unroll
    for (int e = 0; e < 8; ++e) ones[e] = (short)0x3F80;   // bf16 1.0

    // depth-1 prefetch of adj + b-frags (r6-proven rolling shape)
    float4 a0 = *reinterpret_cast<const float4*>(adjp);
    float4 a1 = *reinterpret_cast<const float4*>(adjp + 4);
    short8 b0 = *reinterpret_cast<const short8*>(whp);
    short8 b1 = *reinterpret_cast<const short8*>(whp + 512);
    short8 b2 = *reinterpret_cast<const short8*>(whp + 1024);
    short8 b3 = *reinterpret_cast<const short8*>(whp + 1536);

    #pragma unroll 2
    for (int t = 0; t < 16; ++t) {
        const int tn = (t < 15) ? t + 1 : 15;
        float4 na0 = *reinterpret_cast<const float4*>(adjp + tn * 32);
        float4 na1 = *reinterpret_cast<const float4*>(adjp + tn * 32 + 4);
        const ushort* np = whp + tn * 2048;
        short8 nb0 = *reinterpret_cast<const short8*>(np);
        short8 nb1 = *reinterpret_cast<const short8*>(np + 512);
        short8 nb2 = *reinterpret_cast<const short8*>(np + 1024);
        short8 nb3 = *reinterpret_cast<const short8*>(np + 1536);

        // E2 pairs for this tile's 8 j (LDS, 16-lane broadcast groups)
        const float4* e2q = reinterpret_cast<const float4*>(e2w + t * 32);
        const float4 q0 = e2q[0], q1 = e2q[1], q2 = e2q[2], q3 = e2q[3];

        // P = adj * max(e1p*E2p, e1n*E2n); pack pairs with +0x8000 + v_perm
        uint32_t u0, u1, pk0, pk1, pk2, pk3;
#define WV(AV, P2, N2) (__float_as_uint((AV) * fmaxf(e1p * (P2), e1n * (N2))) + 0x8000u)
        u0 = WV(a0.x, q0.x, q0.y); u1 = WV(a0.y, q0.z, q0.w);
        pk0 = __builtin_amdgcn_perm(u1, u0, 0x07060302);
        u0 = WV(a0.z, q1.x, q1.y); u1 = WV(a0.w, q1.z, q1.w);
        pk1 = __builtin_amdgcn_perm(u1, u0, 0x07060302);
        u0 = WV(a1.x, q2.x, q2.y); u1 = WV(a1.y, q2.z, q2.w);
        pk2 = __builtin_amdgcn_perm(u1, u0, 0x07060302);
        u0 = WV(a1.z, q3.x, q3.y); u1 = WV(a1.w, q3.z, q3.w);
        pk3 = __builtin_amdgcn_perm(u1, u0, 0x07060302);
#undef WV
        int4 afw = make_int4((int)pk0, (int)pk1, (int)pk2, (int)pk3);
        short8 af = *reinterpret_cast<short8*>(&afw);

        acc0 = __builtin_amdgcn_mfma_f32_16x16x32_bf16(af, b0, acc0, 0, 0, 0);
        acc1 = __builtin_amdgcn_mfma_f32_16x16x32_bf16(af, b1, acc1, 0, 0, 0);
        acc2 = __builtin_amdgcn_mfma_f32_16x16x32_bf16(af, b2, acc2, 0, 0, 0);
        acc3 = __builtin_amdgcn_mfma_f32_16x16x32_bf16(af, b3, acc3, 0, 0, 0);
        accS = __builtin_amdgcn_mfma_f32_16x16x32_bf16(af, ones, accS, 0, 0, 0);

        a0 = na0; a1 = na1;
        b0 = nb0; b1 = nb1; b2 = nb2; b3 = nb3;
    }

    // accS is in D layout: accS[r] = S(row lk*4+r) on every lane
    if (li == 0) {
        #pragma unroll
        for (int r = 0; r < 4; ++r) lS[w][lk * 4 + r] = accS[r];
    }
    #pragma unroll
    for (int r = 0; r < 4; ++r) {
        lacc[w][lk * 4 + r][0 * 16 + li] = acc0[r];
        lacc[w][lk * 4 + r][1 * 16 + li] = acc1[r];
        lacc[w][lk * 4 + r][2 * 16 + li] = acc2[r];
        lacc[w][lk * 4 + r][3 * 16 + li] = acc3[r];
    }
    __syncthreads();

    // combine: 1024 outputs, 4 per thread
    #pragma unroll
    for (int q = 0; q < 4; ++q) {
        const int idx = q * 256 + tid;
        const int row = idx >> 6, col = idx & 63;
        float v = lacc[0][row][col] + lacc[1][row][col] + lacc[2][row][col] + lacc[3][row][col];
        float S = lS[0][row] + lS[1][row] + lS[2][row] + lS[3][row];
        float o = v / S;
        o = o > 0.f ? o : expm1f(o);
        out[(size_t)(rowbase + row) * FOUT + col] = o;
    }
}

// ---------------------------------------------------------------------------
extern "C" void kernel_launch(void* const* d_in, const int* in_sizes, int n_in,
                              void* d_out, int out_size, void* d_ws, size_t ws_size,
                              hipStream_t stream) {
    (void)in_sizes; (void)n_in; (void)out_size; (void)ws_size;
    const float* h   = (const float*)d_in[0];
    const float* adj = (const float*)d_in[1];
    const float* W   = (const float*)d_in[2];
    const float* a   = (const float*)d_in[3];
    float* out = (float*)d_out;

    ushort* WhP = (ushort*)d_ws;                          // 2 MB
    float* s1w  = (float*)(WhP + (size_t)BB * NN * FOUT);
    float* s2w  = s1w + (size_t)BB * NN;
    float* pmaxw = s2w + (size_t)BB * NN;                 // NBLK_G floats

    k_gemm_hw<<<NBLK_G, 256, 0, stream>>>(h, W, a, WhP, s1w, s2w, pmaxw);
    k_attn<<<BB * NN / 16, 256, 0, stream>>>(adj, WhP, s1w, s2w, pmaxw, out);
}